// Round 7
// baseline (214.040 us; speedup 1.0000x reference)
//
#include <hip/hip_runtime.h>

typedef _Float16 f16;
typedef f16  f16x8 __attribute__((ext_vector_type(8)));
typedef f16  f16x4 __attribute__((ext_vector_type(4)));
typedef float f32x4 __attribute__((ext_vector_type(4)));
typedef int  i32x4 __attribute__((ext_vector_type(4)));

#define MFMA16(a,b,c) __builtin_amdgcn_mfma_f32_16x16x32_f16((a),(b),(c),0,0,0)
#define EXP2(x) __builtin_amdgcn_exp2f(x)
#define LOG2E 1.44269504089f

static constexpr int Tq   = 2048;  // sequence length
static constexpr int Cdim = 1024;  // model dim
// heads = 16, d_head = 64, batch = 2 (hardcoded below)

// async global->LDS, 16B per lane; dest is wave-uniform base + lane*16
__device__ static inline void gload_lds16(const f16* gsrc, f16* ldst)
{
    __builtin_amdgcn_global_load_lds(
        (const __attribute__((address_space(1))) void*)gsrc,
        (__attribute__((address_space(3))) void*)ldst, 16, 0, 0);
}

// ---------------- x (f32) -> f16 ----------------
__global__ __launch_bounds__(256) void k_cvt_x(const float* __restrict__ x, f16* __restrict__ xh)
{
    int i = blockIdx.x * 256 + threadIdx.x;
    f32x4 v = ((const f32x4*)x)[i];
    f16x4 o; o[0] = (f16)v[0]; o[1] = (f16)v[1]; o[2] = (f16)v[2]; o[3] = (f16)v[3];
    ((f16x4*)xh)[i] = o;
}

// ------------- W (K x N, f32) -> WT (N x K, f16) -------------
__global__ __launch_bounds__(256) void k_trans(const float* __restrict__ W, f16* __restrict__ WT,
                                               int K, int N)
{
    __shared__ float t[64][65];
    int n0 = blockIdx.x * 64, k0 = blockIdx.y * 64;
    int tid = threadIdx.x;
    int lr = tid >> 6, lc = tid & 63;
    #pragma unroll 4
    for (int i = 0; i < 16; i++) {
        int kl = lr * 16 + i;
        t[kl][lc] = W[(size_t)(k0 + kl) * N + n0 + lc];
    }
    __syncthreads();
    #pragma unroll 4
    for (int i = 0; i < 16; i++) {
        int nl = lr * 16 + i;
        WT[(size_t)(n0 + nl) * K + k0 + lc] = (f16)t[lc][nl];
    }
}

// ------------- GEMM: C = A(MxK) * BT(NxK)^T + bias -------------
// m97 structure: global_load_lds(16B) staging, linear LDS dest, pre-swizzled
// global source (chunk ch = pch ^ (row&7)), 2 barriers per K-step.
// EPI 0: write f32 C.  EPI 1: route QKV into Qc/Kc (bh,t,d) and Vt (bh,d,t).
template<int EPI>
__global__ __launch_bounds__(256) void k_gemm(
    const f16* __restrict__ A, const f16* __restrict__ BT, const float* __restrict__ bias,
    float* __restrict__ Cf, f16* __restrict__ Qc, f16* __restrict__ Kc, f16* __restrict__ Vt,
    int N, int K)
{
    __shared__ __align__(16) f16 As[128][64];
    __shared__ __align__(16) f16 Bs[128][64];
    const int tid = threadIdx.x;
    const int lane = tid & 63, wv = tid >> 6;
    const int l16 = lane & 15, lhi = lane >> 4;
    const int wr = wv >> 1, wc = wv & 1;
    const int bm = blockIdx.y * 128, bn = blockIdx.x * 128;

    const int srow = lane >> 3;                 // 0..7 within an issue block
    const int sch  = (lane & 7) ^ (srow & 7);   // pre-swizzled global chunk

    f32x4 acc[4][4] = {};

    for (int kt = 0; kt < K; kt += 64) {
        #pragma unroll
        for (int i = 0; i < 4; i++) {
            int blk = wv * 4 + i;               // 16 blocks of 8 rows
            int row = blk * 8 + srow;
            gload_lds16(A  + (size_t)(bm + row) * K + kt + sch * 8, &As[blk * 8][0]);
            gload_lds16(BT + (size_t)(bn + row) * K + kt + sch * 8, &Bs[blk * 8][0]);
        }
        __syncthreads();                        // drains vmcnt(0): tiles ready
        #pragma unroll
        for (int kk = 0; kk < 2; kk++) {
            f16x8 af[4], bfr[4];
            #pragma unroll
            for (int i = 0; i < 4; i++) {
                int ra = wr * 64 + i * 16 + l16;
                af[i]  = *(const f16x8*)&As[ra][((kk * 4 + lhi) ^ (ra & 7)) * 8];
                int rb = wc * 64 + i * 16 + l16;
                bfr[i] = *(const f16x8*)&Bs[rb][((kk * 4 + lhi) ^ (rb & 7)) * 8];
            }
            #pragma unroll
            for (int i = 0; i < 4; i++)
                #pragma unroll
                for (int j = 0; j < 4; j++)
                    acc[i][j] = MFMA16(af[i], bfr[j], acc[i][j]);
        }
        __syncthreads();                        // all waves done reading LDS
    }

    #pragma unroll
    for (int i = 0; i < 4; i++) {
        int row0 = bm + wr * 64 + i * 16 + lhi * 4;   // +r
        #pragma unroll
        for (int j = 0; j < 4; j++) {
            int col = bn + wc * 64 + j * 16 + l16;
            float bv = bias[col];
            if (EPI == 0) {
                #pragma unroll
                for (int r = 0; r < 4; r++)
                    Cf[(size_t)(row0 + r) * N + col] = acc[i][j][r] + bv;
            } else {
                int b_ = row0 >> 11;          // T = 2048
                int t0 = row0 & 2047;
                int s  = col >> 10;           // 0=Q 1=K 2=V
                int h  = (col >> 6) & 15;
                int d  = col & 63;
                int bh = b_ * 16 + h;
                if (s < 2) {
                    f16* dst = (s == 0 ? Qc : Kc);
                    #pragma unroll
                    for (int r = 0; r < 4; r++)
                        dst[((size_t)bh * Tq + t0 + r) * 64 + d] = (f16)(acc[i][j][r] + bv);
                } else {
                    f16x4 p;
                    #pragma unroll
                    for (int r = 0; r < 4; r++) p[r] = (f16)(acc[i][j][r] + bv);
                    *(f16x4*)&Vt[((size_t)bh * 64 + d) * Tq + t0] = p;
                }
            }
        }
    }
}

// ------------- attention: softmax(Q K^T) V / 8 -> Yc (f16, [b*T][C]) -------------
// Two-sided swap: QK^T = mfma(K, Q) (D col = q), PV = mfma(V, P^T) (D col = q).
// K staged at bit-permuted LDS rows so each lane's 16 P values are exactly its
// PV B-fragment slots -> P stays in-register (8 cvt_pkrtz, zero cross-lane ops).
// LDS double-buffered: ONE barrier per tile; t+1 loads issue before compute,
// ds_write lands after compute (T14), so HBM latency hides under a full tile.
__global__ __launch_bounds__(256) void k_attn(
    const f16* __restrict__ Qc, const f16* __restrict__ Kc, const f16* __restrict__ Vt,
    f16* __restrict__ Yc)
{
    __shared__ __align__(16) f16 Ks[2][64][64];
    __shared__ __align__(16) f16 Vs[2][64][64];

    const int tid = threadIdx.x;
    const int lane = tid & 63, wv = tid >> 6;
    const int l16 = lane & 15, lhi = lane >> 4;
    const int bh = blockIdx.y;
    const int q0 = blockIdx.x * 64;

    const f16* Qh = Qc + (size_t)bh * Tq * 64;
    const f16* Kh = Kc + (size_t)bh * Tq * 64;
    const f16* Vh = Vt + (size_t)bh * 64 * Tq;

    // staging geometry: thread covers rows {row0, row0+32}, 16B chunk ch0
    const int row0 = tid >> 3, ch0 = tid & 7;
    // K LDS row permutation: mem key bits (r4 r3 r2 r1 r0) -> LDS row (r2 r4 r3 r1 r0)
    const int rp0  = (((row0 >> 2) & 1) << 4) | (((row0 >> 4) & 1) << 3)
                   | (((row0 >> 3) & 1) << 2) | (row0 & 3);
    const int pchK = ch0 ^ (rp0 & 7);           // rp0+32 has same low 3 bits
    const int pchV = ch0 ^ (row0 & 7);

    // Q fragments (B operand of QK^T): col = q = q0+wv*16+l16, k = kk*32+lhi*8
    f16x8 qf[2];
    {
        int qrow = q0 + wv * 16 + l16;
        #pragma unroll
        for (int kk = 0; kk < 2; kk++)
            qf[kk] = *(const f16x8*)(Qh + (size_t)qrow * 64 + kk * 32 + lhi * 8);
    }

    f32x4 o[4] = {};              // O[q = l16][d = ct*16 + lhi*4 + r]
    float m2 = -3e38f, l = 0.0f;  // per-lane softmax state for q = l16

    // prologue: tile 0 -> regs -> LDS buf 0
    f16x8 kr0, kr1, vr0, vr1;
    kr0 = *(const f16x8*)(Kh + (size_t)row0 * 64 + ch0 * 8);
    kr1 = *(const f16x8*)(Kh + (size_t)(row0 + 32) * 64 + ch0 * 8);
    vr0 = *(const f16x8*)(Vh + (size_t)row0 * Tq + ch0 * 8);
    vr1 = *(const f16x8*)(Vh + (size_t)(row0 + 32) * Tq + ch0 * 8);
    *(f16x8*)&Ks[0][rp0][pchK * 8]       = kr0;
    *(f16x8*)&Ks[0][rp0 + 32][pchK * 8]  = kr1;
    *(f16x8*)&Vs[0][row0][pchV * 8]      = vr0;
    *(f16x8*)&Vs[0][row0 + 32][pchV * 8] = vr1;
    __syncthreads();

    int cur = 0;
    for (int t = 0; t < 32; t++) {
        if (t < 31) {                          // issue t+1 loads (return hides under compute)
            int kt2 = (t + 1) * 64;
            kr0 = *(const f16x8*)(Kh + (size_t)(kt2 + row0) * 64 + ch0 * 8);
            kr1 = *(const f16x8*)(Kh + (size_t)(kt2 + row0 + 32) * 64 + ch0 * 8);
            vr0 = *(const f16x8*)(Vh + (size_t)row0 * Tq + kt2 + ch0 * 8);
            vr1 = *(const f16x8*)(Vh + (size_t)(row0 + 32) * Tq + kt2 + ch0 * 8);
        }

        const f16 (* __restrict__ Kb)[64] = Ks[cur];
        const f16 (* __restrict__ Vb)[64] = Vs[cur];

        // S^T = K Q  (A = K from permuted LDS rows, B = Q)
        f32x4 s[4];
        __builtin_amdgcn_s_setprio(1);
        #pragma unroll
        for (int ck = 0; ck < 4; ck++) {
            f32x4 acc = {};
            #pragma unroll
            for (int kk = 0; kk < 2; kk++) {
                f16x8 kf = *(const f16x8*)&Kb[ck * 16 + l16][((kk * 4 + lhi) ^ (l16 & 7)) * 8];
                acc = MFMA16(kf, qf[kk], acc);
            }
            s[ck] = acc;
        }
        __builtin_amdgcn_s_setprio(0);
        // lane holds S[q=l16][mem key = 32(ck>>1) + 8*lhi + 4(ck&1) + r]

        // tile max for this lane's q (15 in-lane fmax + 2 shfl over lhi)
        float tm = fmaxf(
            fmaxf(fmaxf(fmaxf(s[0][0], s[0][1]), fmaxf(s[0][2], s[0][3])),
                  fmaxf(fmaxf(s[1][0], s[1][1]), fmaxf(s[1][2], s[1][3]))),
            fmaxf(fmaxf(fmaxf(s[2][0], s[2][1]), fmaxf(s[2][2], s[2][3])),
                  fmaxf(fmaxf(s[3][0], s[3][1]), fmaxf(s[3][2], s[3][3]))));
        tm = fmaxf(tm, __shfl_xor(tm, 16));
        tm = fmaxf(tm, __shfl_xor(tm, 32));

        // defer-max: rescale only when max grows by > 8 (P bounded by e^8 < f16 max)
        if (!__all(tm - m2 <= 8.0f)) {
            float mn = fmaxf(m2, tm);
            float sc = EXP2((m2 - mn) * LOG2E);
            m2 = mn; l *= sc;
            #pragma unroll
            for (int ct = 0; ct < 4; ct++)
                #pragma unroll
                for (int r = 0; r < 4; r++)
                    o[ct][r] *= sc;            // in-lane: o cols are this lane's q
        }

        // P = exp(s - m) via exp2(fma)
        float nm2 = -m2 * LOG2E;
        f32x4 p[4];
        #pragma unroll
        for (int ck = 0; ck < 4; ck++)
            #pragma unroll
            for (int r = 0; r < 4; r++)
                p[ck][r] = EXP2(fmaf(s[ck][r], LOG2E, nm2));

        // l += sum(P) (15 in-lane adds + 2 shfl)
        float su = ((p[0][0] + p[0][1]) + (p[0][2] + p[0][3]))
                 + ((p[1][0] + p[1][1]) + (p[1][2] + p[1][3]))
                 + ((p[2][0] + p[2][1]) + (p[2][2] + p[2][3]))
                 + ((p[3][0] + p[3][1]) + (p[3][2] + p[3][3]));
        su += __shfl_xor(su, 16);
        su += __shfl_xor(su, 32);
        l += su;

        // PV: O^T += V * P^T.  B-frag (P^T) is this lane's own p, packed:
        // slots j=0..7 of MFMA kk2 = (p[2kk2][0..3], p[2kk2+1][0..3])
        __builtin_amdgcn_s_setprio(1);
        #pragma unroll
        for (int kk2 = 0; kk2 < 2; kk2++) {
            i32x4 w;
            w[0] = __builtin_bit_cast(int, __builtin_amdgcn_cvt_pkrtz(p[2*kk2][0],   p[2*kk2][1]));
            w[1] = __builtin_bit_cast(int, __builtin_amdgcn_cvt_pkrtz(p[2*kk2][2],   p[2*kk2][3]));
            w[2] = __builtin_bit_cast(int, __builtin_amdgcn_cvt_pkrtz(p[2*kk2+1][0], p[2*kk2+1][1]));
            w[3] = __builtin_bit_cast(int, __builtin_amdgcn_cvt_pkrtz(p[2*kk2+1][2], p[2*kk2+1][3]));
            f16x8 pb = __builtin_bit_cast(f16x8, w);
            #pragma unroll
            for (int ct = 0; ct < 4; ct++) {
                f16x8 vf = *(const f16x8*)&Vb[ct * 16 + l16][((kk2 * 4 + lhi) ^ (l16 & 7)) * 8];
                o[ct] = MFMA16(vf, pb, o[ct]);
            }
        }
        __builtin_amdgcn_s_setprio(0);

        if (t < 31) {                          // write t+1 into other buffer, then ONE barrier
            int nxt = cur ^ 1;
            *(f16x8*)&Ks[nxt][rp0][pchK * 8]       = kr0;
            *(f16x8*)&Ks[nxt][rp0 + 32][pchK * 8]  = kr1;
            *(f16x8*)&Vs[nxt][row0][pchV * 8]      = vr0;
            *(f16x8*)&Vs[nxt][row0 + 32][pchV * 8] = vr1;
            __syncthreads();
            cur = nxt;
        }
    }

    // epilogue: y = o / l / 8; o[ct][r] = O[q=l16][d=ct*16+lhi*4+r] -> f16x4 stores
    const int b_ = bh >> 4, h_ = bh & 15;
    const int q  = q0 + wv * 16 + l16;
    const float inv = 1.0f / (l * 8.0f);
    size_t rb = (size_t)(b_ * Tq + q) * Cdim + h_ * 64;
    #pragma unroll
    for (int ct = 0; ct < 4; ct++) {
        f16x4 y;
        #pragma unroll
        for (int r = 0; r < 4; r++) y[r] = (f16)(o[ct][r] * inv);
        *(f16x4*)&Yc[rb + ct * 16 + lhi * 4] = y;
    }
}

extern "C" void kernel_launch(void* const* d_in, const int* in_sizes, int n_in,
                              void* d_out, int out_size, void* d_ws, size_t ws_size,
                              hipStream_t stream)
{
    (void)in_sizes; (void)n_in; (void)out_size; (void)ws_size;
    const float* x  = (const float*)d_in[0];
    const float* Wa = (const float*)d_in[1];
    const float* ba = (const float*)d_in[2];
    const float* Wp = (const float*)d_in[3];
    const float* bp = (const float*)d_in[4];
    float* out = (float*)d_out;

    char* ws = (char*)d_ws;               // needs 48 MB
    f16* Xh  = (f16*)(ws);                //  8 MB  [4096][1024]
    f16* WaT = (f16*)(ws + (8u  << 20));  //  6 MB  [3072][1024]
    f16* WpT = (f16*)(ws + (14u << 20));  //  2 MB  [1024][1024]
    f16* Qc  = (f16*)(ws + (16u << 20));  //  8 MB  [32][2048][64]
    f16* Kc  = (f16*)(ws + (24u << 20));  //  8 MB  [32][2048][64]
    f16* Vt  = (f16*)(ws + (32u << 20));  //  8 MB  [32][64][2048]
    f16* Yc  = (f16*)(ws + (40u << 20));  //  8 MB  [4096][1024]

    k_cvt_x<<<4096, 256, 0, stream>>>(x, Xh);
    k_trans<<<dim3(48, 16), 256, 0, stream>>>(Wa, WaT, 1024, 3072);
    k_trans<<<dim3(16, 16), 256, 0, stream>>>(Wp, WpT, 1024, 1024);
    k_gemm<1><<<dim3(24, 32), 256, 0, stream>>>(Xh, WaT, ba, nullptr, Qc, Kc, Vt, 3072, 1024);
    k_attn<<<dim3(32, 32), 256, 0, stream>>>(Qc, Kc, Vt, Yc);
    k_gemm<0><<<dim3(8, 32), 256, 0, stream>>>(Yc, WpT, bp, out, nullptr, nullptr, nullptr, 1024, 1024);
}

// Round 9
// 208.632 us; speedup vs baseline: 1.0259x; 1.0259x over previous
//
#include <hip/hip_runtime.h>

typedef _Float16 f16;
typedef f16  f16x8 __attribute__((ext_vector_type(8)));
typedef f16  f16x4 __attribute__((ext_vector_type(4)));
typedef float f32x4 __attribute__((ext_vector_type(4)));
typedef int  i32x4 __attribute__((ext_vector_type(4)));

#define MFMA16(a,b,c) __builtin_amdgcn_mfma_f32_16x16x32_f16((a),(b),(c),0,0,0)
#define EXP2(x) __builtin_amdgcn_exp2f(x)
#define LOG2E 1.44269504089f

static constexpr int Tq   = 2048;  // sequence length
static constexpr int Cdim = 1024;  // model dim
// heads = 16, d_head = 64, batch = 2 (hardcoded below)

// async global->LDS, 16B per lane; dest is wave-uniform base + lane*16
__device__ static inline void gload_lds16(const f16* gsrc, f16* ldst)
{
    __builtin_amdgcn_global_load_lds(
        (const __attribute__((address_space(1))) void*)gsrc,
        (__attribute__((address_space(3))) void*)ldst, 16, 0, 0);
}

// ---------------- x (f32) -> f16 ----------------
__global__ __launch_bounds__(256) void k_cvt_x(const float* __restrict__ x, f16* __restrict__ xh)
{
    int i = blockIdx.x * 256 + threadIdx.x;
    f32x4 v = ((const f32x4*)x)[i];
    f16x4 o; o[0] = (f16)v[0]; o[1] = (f16)v[1]; o[2] = (f16)v[2]; o[3] = (f16)v[3];
    ((f16x4*)xh)[i] = o;
}

// ------------- W (K x N, f32) -> WT (N x K, f16) -------------
__global__ __launch_bounds__(256) void k_trans(const float* __restrict__ W, f16* __restrict__ WT,
                                               int K, int N)
{
    __shared__ float t[64][65];
    int n0 = blockIdx.x * 64, k0 = blockIdx.y * 64;
    int tid = threadIdx.x;
    int lr = tid >> 6, lc = tid & 63;
    #pragma unroll 4
    for (int i = 0; i < 16; i++) {
        int kl = lr * 16 + i;
        t[kl][lc] = W[(size_t)(k0 + kl) * N + n0 + lc];
    }
    __syncthreads();
    #pragma unroll 4
    for (int i = 0; i < 16; i++) {
        int nl = lr * 16 + i;
        WT[(size_t)(n0 + nl) * K + k0 + lc] = (f16)t[lc][nl];
    }
}

// ------------- GEMM: C = A(MxK) * BT(NxK)^T + bias -------------
// m97 structure: global_load_lds(16B) staging, linear LDS dest, pre-swizzled
// global source (chunk ch = pch ^ (row&7)), 2 barriers per K-step.
// EPI 0: write f32 C.  EPI 1: route QKV into Qc/Kc (bh,t,d) and Vt (bh,d,t).
template<int EPI>
__global__ __launch_bounds__(256) void k_gemm(
    const f16* __restrict__ A, const f16* __restrict__ BT, const float* __restrict__ bias,
    float* __restrict__ Cf, f16* __restrict__ Qc, f16* __restrict__ Kc, f16* __restrict__ Vt,
    int N, int K)
{
    __shared__ __align__(16) f16 As[128][64];
    __shared__ __align__(16) f16 Bs[128][64];
    const int tid = threadIdx.x;
    const int lane = tid & 63, wv = tid >> 6;
    const int l16 = lane & 15, lhi = lane >> 4;
    const int wr = wv >> 1, wc = wv & 1;
    const int bm = blockIdx.y * 128, bn = blockIdx.x * 128;

    const int srow = lane >> 3;                 // 0..7 within an issue block
    const int sch  = (lane & 7) ^ (srow & 7);   // pre-swizzled global chunk

    f32x4 acc[4][4] = {};

    for (int kt = 0; kt < K; kt += 64) {
        #pragma unroll
        for (int i = 0; i < 4; i++) {
            int blk = wv * 4 + i;               // 16 blocks of 8 rows
            int row = blk * 8 + srow;
            gload_lds16(A  + (size_t)(bm + row) * K + kt + sch * 8, &As[blk * 8][0]);
            gload_lds16(BT + (size_t)(bn + row) * K + kt + sch * 8, &Bs[blk * 8][0]);
        }
        __syncthreads();                        // drains vmcnt(0): tiles ready
        #pragma unroll
        for (int kk = 0; kk < 2; kk++) {
            f16x8 af[4], bfr[4];
            #pragma unroll
            for (int i = 0; i < 4; i++) {
                int ra = wr * 64 + i * 16 + l16;
                af[i]  = *(const f16x8*)&As[ra][((kk * 4 + lhi) ^ (ra & 7)) * 8];
                int rb = wc * 64 + i * 16 + l16;
                bfr[i] = *(const f16x8*)&Bs[rb][((kk * 4 + lhi) ^ (rb & 7)) * 8];
            }
            #pragma unroll
            for (int i = 0; i < 4; i++)
                #pragma unroll
                for (int j = 0; j < 4; j++)
                    acc[i][j] = MFMA16(af[i], bfr[j], acc[i][j]);
        }
        __syncthreads();                        // all waves done reading LDS
    }

    #pragma unroll
    for (int i = 0; i < 4; i++) {
        int row0 = bm + wr * 64 + i * 16 + lhi * 4;   // +r
        #pragma unroll
        for (int j = 0; j < 4; j++) {
            int col = bn + wc * 64 + j * 16 + l16;
            float bv = bias[col];
            if (EPI == 0) {
                #pragma unroll
                for (int r = 0; r < 4; r++)
                    Cf[(size_t)(row0 + r) * N + col] = acc[i][j][r] + bv;
            } else {
                int b_ = row0 >> 11;          // T = 2048
                int t0 = row0 & 2047;
                int s  = col >> 10;           // 0=Q 1=K 2=V
                int h  = (col >> 6) & 15;
                int d  = col & 63;
                int bh = b_ * 16 + h;
                if (s < 2) {
                    f16* dst = (s == 0 ? Qc : Kc);
                    #pragma unroll
                    for (int r = 0; r < 4; r++)
                        dst[((size_t)bh * Tq + t0 + r) * 64 + d] = (f16)(acc[i][j][r] + bv);
                } else {
                    f16x4 p;
                    #pragma unroll
                    for (int r = 0; r < 4; r++) p[r] = (f16)(acc[i][j][r] + bv);
                    *(f16x4*)&Vt[((size_t)bh * 64 + d) * Tq + t0] = p;
                }
            }
        }
    }
}

// ------------- attention: softmax(Q K^T) V / 8 -> Yc (f16, [b*T][C]) -------------
// Two-sided swap, 32 q per wave (two B-fragments), 128-q block.
// K/V fragments are shared by both q-groups: 16 ds_read feed 32 MFMA per tile.
// The two q-streams are independent -> in-wave MFMA/VALU overlap.
__global__ __launch_bounds__(256) void k_attn(
    const f16* __restrict__ Qc, const f16* __restrict__ Kc, const f16* __restrict__ Vt,
    f16* __restrict__ Yc)
{
    __shared__ __align__(16) f16 Ks[2][64][64];
    __shared__ __align__(16) f16 Vs[2][64][64];

    const int tid = threadIdx.x;
    const int lane = tid & 63, wv = tid >> 6;
    const int l16 = lane & 15, lhi = lane >> 4;
    const int bh = blockIdx.y;
    const int q0 = blockIdx.x * 128;

    const f16* Qh = Qc + (size_t)bh * Tq * 64;
    const f16* Kh = Kc + (size_t)bh * Tq * 64;
    const f16* Vh = Vt + (size_t)bh * 64 * Tq;

    // staging geometry: thread covers rows {row0, row0+32}, 16B chunk ch0
    const int row0 = tid >> 3, ch0 = tid & 7;
    // K LDS row permutation: mem key bits (r4 r3 r2 r1 r0) -> LDS row (r2 r4 r3 r1 r0)
    const int rp0  = (((row0 >> 2) & 1) << 4) | (((row0 >> 4) & 1) << 3)
                   | (((row0 >> 3) & 1) << 2) | (row0 & 3);
    const int pchK = ch0 ^ (rp0 & 7);           // rp0+32 has same low 3 bits
    const int pchV = ch0 ^ (row0 & 7);

    // Q fragments (B operand of QK^T): qg selects the 16-q group
    f16x8 qf[2][2];
    #pragma unroll
    for (int qg = 0; qg < 2; qg++) {
        int qrow = q0 + wv * 32 + qg * 16 + l16;
        #pragma unroll
        for (int kk = 0; kk < 2; kk++)
            qf[qg][kk] = *(const f16x8*)(Qh + (size_t)qrow * 64 + kk * 32 + lhi * 8);
    }

    f32x4 o[2][4] = {};                       // O[qg][q=l16][d = ct*16 + lhi*4 + r]
    float m2[2] = {-3e38f, -3e38f}, l[2] = {0.0f, 0.0f};

    // prologue: tile 0 -> regs -> LDS buf 0
    f16x8 kr0, kr1, vr0, vr1;
    kr0 = *(const f16x8*)(Kh + (size_t)row0 * 64 + ch0 * 8);
    kr1 = *(const f16x8*)(Kh + (size_t)(row0 + 32) * 64 + ch0 * 8);
    vr0 = *(const f16x8*)(Vh + (size_t)row0 * Tq + ch0 * 8);
    vr1 = *(const f16x8*)(Vh + (size_t)(row0 + 32) * Tq + ch0 * 8);
    *(f16x8*)&Ks[0][rp0][pchK * 8]       = kr0;
    *(f16x8*)&Ks[0][rp0 + 32][pchK * 8]  = kr1;
    *(f16x8*)&Vs[0][row0][pchV * 8]      = vr0;
    *(f16x8*)&Vs[0][row0 + 32][pchV * 8] = vr1;
    __syncthreads();

    int cur = 0;
    for (int t = 0; t < 32; t++) {
        if (t < 31) {                          // issue t+1 loads (return hides under compute)
            int kt2 = (t + 1) * 64;
            kr0 = *(const f16x8*)(Kh + (size_t)(kt2 + row0) * 64 + ch0 * 8);
            kr1 = *(const f16x8*)(Kh + (size_t)(kt2 + row0 + 32) * 64 + ch0 * 8);
            vr0 = *(const f16x8*)(Vh + (size_t)row0 * Tq + kt2 + ch0 * 8);
            vr1 = *(const f16x8*)(Vh + (size_t)(row0 + 32) * Tq + kt2 + ch0 * 8);
        }

        const f16 (* __restrict__ Kb)[64] = Ks[cur];
        const f16 (* __restrict__ Vb)[64] = Vs[cur];

        // S^T = K Q: kf shared by both q-groups (8 ds_read -> 16 MFMA)
        f32x4 s[2][4] = {};
        __builtin_amdgcn_s_setprio(1);
        #pragma unroll
        for (int ck = 0; ck < 4; ck++) {
            #pragma unroll
            for (int kk = 0; kk < 2; kk++) {
                f16x8 kf = *(const f16x8*)&Kb[ck * 16 + l16][((kk * 4 + lhi) ^ (l16 & 7)) * 8];
                s[0][ck] = MFMA16(kf, qf[0][kk], s[0][ck]);
                s[1][ck] = MFMA16(kf, qf[1][kk], s[1][ck]);
            }
        }
        __builtin_amdgcn_s_setprio(0);
        // lane holds S[qg][q=l16][mem key = 32(ck>>1) + 8*lhi + 4(ck&1) + r]

        // tile max per qg (15 in-lane fmax + 2 shfl over lhi)
        float tm[2];
        #pragma unroll
        for (int qg = 0; qg < 2; qg++) {
            float v = fmaxf(
                fmaxf(fmaxf(fmaxf(s[qg][0][0], s[qg][0][1]), fmaxf(s[qg][0][2], s[qg][0][3])),
                      fmaxf(fmaxf(s[qg][1][0], s[qg][1][1]), fmaxf(s[qg][1][2], s[qg][1][3]))),
                fmaxf(fmaxf(fmaxf(s[qg][2][0], s[qg][2][1]), fmaxf(s[qg][2][2], s[qg][2][3])),
                      fmaxf(fmaxf(s[qg][3][0], s[qg][3][1]), fmaxf(s[qg][3][2], s[qg][3][3]))));
            v = fmaxf(v, __shfl_xor(v, 16));
            v = fmaxf(v, __shfl_xor(v, 32));
            tm[qg] = v;
        }

        // defer-max: rescale only when either group's max grows by > 8
        if (!__all((tm[0] - m2[0] <= 8.0f) && (tm[1] - m2[1] <= 8.0f))) {
            #pragma unroll
            for (int qg = 0; qg < 2; qg++) {
                float mn = fmaxf(m2[qg], tm[qg]);
                float sc = EXP2((m2[qg] - mn) * LOG2E);
                m2[qg] = mn; l[qg] *= sc;
                #pragma unroll
                for (int ct = 0; ct < 4; ct++)
                    #pragma unroll
                    for (int r = 0; r < 4; r++)
                        o[qg][ct][r] *= sc;
            }
        }

        // P = exp(s - m) in place; l += sum(P)
        #pragma unroll
        for (int qg = 0; qg < 2; qg++) {
            float nm2 = -m2[qg] * LOG2E;
            #pragma unroll
            for (int ck = 0; ck < 4; ck++)
                #pragma unroll
                for (int r = 0; r < 4; r++)
                    s[qg][ck][r] = EXP2(fmaf(s[qg][ck][r], LOG2E, nm2));
            float su = ((s[qg][0][0] + s[qg][0][1]) + (s[qg][0][2] + s[qg][0][3]))
                     + ((s[qg][1][0] + s[qg][1][1]) + (s[qg][1][2] + s[qg][1][3]))
                     + ((s[qg][2][0] + s[qg][2][1]) + (s[qg][2][2] + s[qg][2][3]))
                     + ((s[qg][3][0] + s[qg][3][1]) + (s[qg][3][2] + s[qg][3][3]));
            su += __shfl_xor(su, 16);
            su += __shfl_xor(su, 32);
            l[qg] += su;
        }

        // PV: O^T += V * P^T.  vf shared by both q-groups (8 ds_read -> 16 MFMA)
        __builtin_amdgcn_s_setprio(1);
        #pragma unroll
        for (int kk2 = 0; kk2 < 2; kk2++) {
            f16x8 pb[2];
            #pragma unroll
            for (int qg = 0; qg < 2; qg++) {
                i32x4 w;
                w[0] = __builtin_bit_cast(int, __builtin_amdgcn_cvt_pkrtz(s[qg][2*kk2][0],   s[qg][2*kk2][1]));
                w[1] = __builtin_bit_cast(int, __builtin_amdgcn_cvt_pkrtz(s[qg][2*kk2][2],   s[qg][2*kk2][3]));
                w[2] = __builtin_bit_cast(int, __builtin_amdgcn_cvt_pkrtz(s[qg][2*kk2+1][0], s[qg][2*kk2+1][1]));
                w[3] = __builtin_bit_cast(int, __builtin_amdgcn_cvt_pkrtz(s[qg][2*kk2+1][2], s[qg][2*kk2+1][3]));
                pb[qg] = __builtin_bit_cast(f16x8, w);
            }
            #pragma unroll
            for (int ct = 0; ct < 4; ct++) {
                f16x8 vf = *(const f16x8*)&Vb[ct * 16 + l16][((kk2 * 4 + lhi) ^ (l16 & 7)) * 8];
                o[0][ct] = MFMA16(vf, pb[0], o[0][ct]);
                o[1][ct] = MFMA16(vf, pb[1], o[1][ct]);
            }
        }
        __builtin_amdgcn_s_setprio(0);

        if (t < 31) {                          // write t+1 into other buffer, then ONE barrier
            int nxt = cur ^ 1;
            *(f16x8*)&Ks[nxt][rp0][pchK * 8]       = kr0;
            *(f16x8*)&Ks[nxt][rp0 + 32][pchK * 8]  = kr1;
            *(f16x8*)&Vs[nxt][row0][pchV * 8]      = vr0;
            *(f16x8*)&Vs[nxt][row0 + 32][pchV * 8] = vr1;
            __syncthreads();
            cur = nxt;
        }
    }

    // epilogue: y = o / l / 8 per q-group
    const int b_ = bh >> 4, h_ = bh & 15;
    #pragma unroll
    for (int qg = 0; qg < 2; qg++) {
        const int q = q0 + wv * 32 + qg * 16 + l16;
        const float inv = 1.0f / (l[qg] * 8.0f);
        size_t rb = (size_t)(b_ * Tq + q) * Cdim + h_ * 64;
        #pragma unroll
        for (int ct = 0; ct < 4; ct++) {
            f16x4 y;
            #pragma unroll
            for (int r = 0; r < 4; r++) y[r] = (f16)(o[qg][ct][r] * inv);
            *(f16x4*)&Yc[rb + ct * 16 + lhi * 4] = y;
        }
    }
}

extern "C" void kernel_launch(void* const* d_in, const int* in_sizes, int n_in,
                              void* d_out, int out_size, void* d_ws, size_t ws_size,
                              hipStream_t stream)
{
    (void)in_sizes; (void)n_in; (void)out_size; (void)ws_size;
    const float* x  = (const float*)d_in[0];
    const float* Wa = (const float*)d_in[1];
    const float* ba = (const float*)d_in[2];
    const float* Wp = (const float*)d_in[3];
    const float* bp = (const float*)d_in[4];
    float* out = (float*)d_out;

    char* ws = (char*)d_ws;               // needs 48 MB
    f16* Xh  = (f16*)(ws);                //  8 MB  [4096][1024]
    f16* WaT = (f16*)(ws + (8u  << 20));  //  6 MB  [3072][1024]
    f16* WpT = (f16*)(ws + (14u << 20));  //  2 MB  [1024][1024]
    f16* Qc  = (f16*)(ws + (16u << 20));  //  8 MB  [32][2048][64]
    f16* Kc  = (f16*)(ws + (24u << 20));  //  8 MB  [32][2048][64]
    f16* Vt  = (f16*)(ws + (32u << 20));  //  8 MB  [32][64][2048]
    f16* Yc  = (f16*)(ws + (40u << 20));  //  8 MB  [4096][1024]

    k_cvt_x<<<4096, 256, 0, stream>>>(x, Xh);
    k_trans<<<dim3(48, 16), 256, 0, stream>>>(Wa, WaT, 1024, 3072);
    k_trans<<<dim3(16, 16), 256, 0, stream>>>(Wp, WpT, 1024, 1024);
    k_gemm<1><<<dim3(24, 32), 256, 0, stream>>>(Xh, WaT, ba, nullptr, Qc, Kc, Vt, 3072, 1024);
    k_attn<<<dim3(16, 32), 256, 0, stream>>>(Qc, Kc, Vt, Yc);
    k_gemm<0><<<dim3(8, 32), 256, 0, stream>>>(Yc, WpT, bp, out, nullptr, nullptr, nullptr, 1024, 1024);
}

// Round 10
// 197.746 us; speedup vs baseline: 1.0824x; 1.0551x over previous
//
#include <hip/hip_runtime.h>

typedef _Float16 f16;
typedef f16  f16x8 __attribute__((ext_vector_type(8)));
typedef f16  f16x4 __attribute__((ext_vector_type(4)));
typedef float f32x4 __attribute__((ext_vector_type(4)));
typedef int  i32x4 __attribute__((ext_vector_type(4)));

#define MFMA16(a,b,c) __builtin_amdgcn_mfma_f32_16x16x32_f16((a),(b),(c),0,0,0)
#define EXP2(x) __builtin_amdgcn_exp2f(x)
#define LOG2E 1.44269504089f

static constexpr int Tq   = 2048;  // sequence length
static constexpr int Cdim = 1024;  // model dim
// heads = 16, d_head = 64, batch = 2 (hardcoded below)

// async global->LDS, 16B per lane; dest is wave-uniform base + lane*16
__device__ static inline void gload_lds16(const f16* gsrc, f16* ldst)
{
    __builtin_amdgcn_global_load_lds(
        (const __attribute__((address_space(1))) void*)gsrc,
        (__attribute__((address_space(3))) void*)ldst, 16, 0, 0);
}

// ---------------- x (f32) -> f16 ----------------
__global__ __launch_bounds__(256) void k_cvt_x(const float* __restrict__ x, f16* __restrict__ xh)
{
    int i = blockIdx.x * 256 + threadIdx.x;
    f32x4 v = ((const f32x4*)x)[i];
    f16x4 o; o[0] = (f16)v[0]; o[1] = (f16)v[1]; o[2] = (f16)v[2]; o[3] = (f16)v[3];
    ((f16x4*)xh)[i] = o;
}

// ------------- W (K x N, f32) -> WT (N x K, f16) -------------
__global__ __launch_bounds__(256) void k_trans(const float* __restrict__ W, f16* __restrict__ WT,
                                               int K, int N)
{
    __shared__ float t[64][65];
    int n0 = blockIdx.x * 64, k0 = blockIdx.y * 64;
    int tid = threadIdx.x;
    int lr = tid >> 6, lc = tid & 63;
    #pragma unroll 4
    for (int i = 0; i < 16; i++) {
        int kl = lr * 16 + i;
        t[kl][lc] = W[(size_t)(k0 + kl) * N + n0 + lc];
    }
    __syncthreads();
    #pragma unroll 4
    for (int i = 0; i < 16; i++) {
        int nl = lr * 16 + i;
        WT[(size_t)(n0 + nl) * K + k0 + lc] = (f16)t[lc][nl];
    }
}

// ------------- GEMM 128x128: QKV (EPI=1 routing epilogue) -------------
template<int EPI>
__global__ __launch_bounds__(256) void k_gemm(
    const f16* __restrict__ A, const f16* __restrict__ BT, const float* __restrict__ bias,
    float* __restrict__ Cf, f16* __restrict__ Qc, f16* __restrict__ Kc, f16* __restrict__ Vt,
    int N, int K)
{
    __shared__ __align__(16) f16 As[128][64];
    __shared__ __align__(16) f16 Bs[128][64];
    const int tid = threadIdx.x;
    const int lane = tid & 63, wv = tid >> 6;
    const int l16 = lane & 15, lhi = lane >> 4;
    const int wr = wv >> 1, wc = wv & 1;
    const int bm = blockIdx.y * 128, bn = blockIdx.x * 128;

    const int srow = lane >> 3;                 // 0..7 within an issue block
    const int sch  = (lane & 7) ^ (srow & 7);   // pre-swizzled global chunk

    f32x4 acc[4][4] = {};

    for (int kt = 0; kt < K; kt += 64) {
        #pragma unroll
        for (int i = 0; i < 4; i++) {
            int blk = wv * 4 + i;               // 16 blocks of 8 rows
            int row = blk * 8 + srow;
            gload_lds16(A  + (size_t)(bm + row) * K + kt + sch * 8, &As[blk * 8][0]);
            gload_lds16(BT + (size_t)(bn + row) * K + kt + sch * 8, &Bs[blk * 8][0]);
        }
        __syncthreads();                        // drains vmcnt(0): tiles ready
        #pragma unroll
        for (int kk = 0; kk < 2; kk++) {
            f16x8 af[4], bfr[4];
            #pragma unroll
            for (int i = 0; i < 4; i++) {
                int ra = wr * 64 + i * 16 + l16;
                af[i]  = *(const f16x8*)&As[ra][((kk * 4 + lhi) ^ (ra & 7)) * 8];
                int rb = wc * 64 + i * 16 + l16;
                bfr[i] = *(const f16x8*)&Bs[rb][((kk * 4 + lhi) ^ (rb & 7)) * 8];
            }
            #pragma unroll
            for (int i = 0; i < 4; i++)
                #pragma unroll
                for (int j = 0; j < 4; j++)
                    acc[i][j] = MFMA16(af[i], bfr[j], acc[i][j]);
        }
        __syncthreads();                        // all waves done reading LDS
    }

    #pragma unroll
    for (int i = 0; i < 4; i++) {
        int row0 = bm + wr * 64 + i * 16 + lhi * 4;   // +r
        #pragma unroll
        for (int j = 0; j < 4; j++) {
            int col = bn + wc * 64 + j * 16 + l16;
            float bv = bias[col];
            if (EPI == 0) {
                #pragma unroll
                for (int r = 0; r < 4; r++)
                    Cf[(size_t)(row0 + r) * N + col] = acc[i][j][r] + bv;
            } else {
                int b_ = row0 >> 11;          // T = 2048
                int t0 = row0 & 2047;
                int s  = col >> 10;           // 0=Q 1=K 2=V
                int h  = (col >> 6) & 15;
                int d  = col & 63;
                int bh = b_ * 16 + h;
                if (s < 2) {
                    f16* dst = (s == 0 ? Qc : Kc);
                    #pragma unroll
                    for (int r = 0; r < 4; r++)
                        dst[((size_t)bh * Tq + t0 + r) * 64 + d] = (f16)(acc[i][j][r] + bv);
                } else {
                    f16x4 p;
                    #pragma unroll
                    for (int r = 0; r < 4; r++) p[r] = (f16)(acc[i][j][r] + bv);
                    *(f16x4*)&Vt[((size_t)bh * 64 + d) * Tq + t0] = p;
                }
            }
        }
    }
}

// ------------- GEMM 128x64 (proj): higher-occupancy tile for N=1024 -------------
// Grid (N/64, M/128), 512 blocks -> 2 blocks/CU (vs 1 with 128x128).
__global__ __launch_bounds__(256) void k_gemmB(
    const f16* __restrict__ A, const f16* __restrict__ BT, const float* __restrict__ bias,
    float* __restrict__ Cf, int N, int K)
{
    __shared__ __align__(16) f16 As[128][64];
    __shared__ __align__(16) f16 Bs[64][64];
    const int tid = threadIdx.x;
    const int lane = tid & 63, wv = tid >> 6;
    const int l16 = lane & 15, lhi = lane >> 4;
    const int bm = blockIdx.y * 128, bn = blockIdx.x * 64;

    const int srow = lane >> 3;
    const int sch  = (lane & 7) ^ (srow & 7);

    f32x4 acc[2][4] = {};                      // wave covers M rows [wv*32, wv*32+32) x 64 N

    for (int kt = 0; kt < K; kt += 64) {
        #pragma unroll
        for (int i = 0; i < 4; i++) {          // A: 16 blocks of 8 rows, 4 per wave
            int blk = wv * 4 + i;
            int row = blk * 8 + srow;
            gload_lds16(A + (size_t)(bm + row) * K + kt + sch * 8, &As[blk * 8][0]);
        }
        #pragma unroll
        for (int i = 0; i < 2; i++) {          // B: 8 blocks of 8 rows, 2 per wave
            int blk = wv * 2 + i;
            int row = blk * 8 + srow;
            gload_lds16(BT + (size_t)(bn + row) * K + kt + sch * 8, &Bs[blk * 8][0]);
        }
        __syncthreads();
        #pragma unroll
        for (int kk = 0; kk < 2; kk++) {
            f16x8 af[2], bfr[4];
            #pragma unroll
            for (int i = 0; i < 2; i++) {
                int ra = wv * 32 + i * 16 + l16;
                af[i] = *(const f16x8*)&As[ra][((kk * 4 + lhi) ^ (ra & 7)) * 8];
            }
            #pragma unroll
            for (int j = 0; j < 4; j++) {
                int rb = j * 16 + l16;
                bfr[j] = *(const f16x8*)&Bs[rb][((kk * 4 + lhi) ^ (rb & 7)) * 8];
            }
            #pragma unroll
            for (int i = 0; i < 2; i++)
                #pragma unroll
                for (int j = 0; j < 4; j++)
                    acc[i][j] = MFMA16(af[i], bfr[j], acc[i][j]);
        }
        __syncthreads();
    }

    #pragma unroll
    for (int i = 0; i < 2; i++) {
        int row0 = bm + wv * 32 + i * 16 + lhi * 4;
        #pragma unroll
        for (int j = 0; j < 4; j++) {
            int col = bn + j * 16 + l16;
            float bv = bias[col];
            #pragma unroll
            for (int r = 0; r < 4; r++)
                Cf[(size_t)(row0 + r) * N + col] = acc[i][j][r] + bv;
        }
    }
}

// ------------- attention: softmax(Q K^T) V / 8 -> Yc (f16, [b*T][C]) -------------
// Two-sided swap, 32 q per wave.  Steady-state tiles use ZERO cross-lane ops:
// per-lane local max drives the __all trigger (equivalent to full-row max test);
// l is kept as per-lane partial (rescale factors are lane-uniform per q) and
// reduced once in the epilogue.  Cross-lhi max reduce only in the rare rescale.
__global__ __launch_bounds__(256) void k_attn(
    const f16* __restrict__ Qc, const f16* __restrict__ Kc, const f16* __restrict__ Vt,
    f16* __restrict__ Yc)
{
    __shared__ __align__(16) f16 Ks[2][64][64];
    __shared__ __align__(16) f16 Vs[2][64][64];

    const int tid = threadIdx.x;
    const int lane = tid & 63, wv = tid >> 6;
    const int l16 = lane & 15, lhi = lane >> 4;
    const int bh = blockIdx.y;
    const int q0 = blockIdx.x * 128;

    const f16* Qh = Qc + (size_t)bh * Tq * 64;
    const f16* Kh = Kc + (size_t)bh * Tq * 64;
    const f16* Vh = Vt + (size_t)bh * 64 * Tq;

    const int row0 = tid >> 3, ch0 = tid & 7;
    // K LDS row permutation: mem key bits (r4 r3 r2 r1 r0) -> LDS row (r2 r4 r3 r1 r0)
    const int rp0  = (((row0 >> 2) & 1) << 4) | (((row0 >> 4) & 1) << 3)
                   | (((row0 >> 3) & 1) << 2) | (row0 & 3);
    const int pchK = ch0 ^ (rp0 & 7);
    const int pchV = ch0 ^ (row0 & 7);

    // Q fragments (B operand of QK^T): qg selects the 16-q group
    f16x8 qf[2][2];
    #pragma unroll
    for (int qg = 0; qg < 2; qg++) {
        int qrow = q0 + wv * 32 + qg * 16 + l16;
        #pragma unroll
        for (int kk = 0; kk < 2; kk++)
            qf[qg][kk] = *(const f16x8*)(Qh + (size_t)qrow * 64 + kk * 32 + lhi * 8);
    }

    f32x4 o[2][4] = {};                       // O[qg][q=l16][d = ct*16 + lhi*4 + r]
    float m2[2] = {-3e38f, -3e38f}, l[2] = {0.0f, 0.0f};  // m2 lane-uniform per q; l per-lane partial

    // prologue: tile 0 -> regs -> LDS buf 0
    f16x8 kr0, kr1, vr0, vr1;
    kr0 = *(const f16x8*)(Kh + (size_t)row0 * 64 + ch0 * 8);
    kr1 = *(const f16x8*)(Kh + (size_t)(row0 + 32) * 64 + ch0 * 8);
    vr0 = *(const f16x8*)(Vh + (size_t)row0 * Tq + ch0 * 8);
    vr1 = *(const f16x8*)(Vh + (size_t)(row0 + 32) * Tq + ch0 * 8);
    *(f16x8*)&Ks[0][rp0][pchK * 8]       = kr0;
    *(f16x8*)&Ks[0][rp0 + 32][pchK * 8]  = kr1;
    *(f16x8*)&Vs[0][row0][pchV * 8]      = vr0;
    *(f16x8*)&Vs[0][row0 + 32][pchV * 8] = vr1;
    __syncthreads();

    int cur = 0;
    for (int t = 0; t < 32; t++) {
        if (t < 31) {                          // issue t+1 loads (return hides under compute)
            int kt2 = (t + 1) * 64;
            kr0 = *(const f16x8*)(Kh + (size_t)(kt2 + row0) * 64 + ch0 * 8);
            kr1 = *(const f16x8*)(Kh + (size_t)(kt2 + row0 + 32) * 64 + ch0 * 8);
            vr0 = *(const f16x8*)(Vh + (size_t)row0 * Tq + kt2 + ch0 * 8);
            vr1 = *(const f16x8*)(Vh + (size_t)(row0 + 32) * Tq + kt2 + ch0 * 8);
        }

        const f16 (* __restrict__ Kb)[64] = Ks[cur];
        const f16 (* __restrict__ Vb)[64] = Vs[cur];

        // S^T = K Q: kf shared by both q-groups (8 ds_read -> 16 MFMA)
        f32x4 s[2][4] = {};
        __builtin_amdgcn_s_setprio(1);
        #pragma unroll
        for (int ck = 0; ck < 4; ck++) {
            #pragma unroll
            for (int kk = 0; kk < 2; kk++) {
                f16x8 kf = *(const f16x8*)&Kb[ck * 16 + l16][((kk * 4 + lhi) ^ (l16 & 7)) * 8];
                s[0][ck] = MFMA16(kf, qf[0][kk], s[0][ck]);
                s[1][ck] = MFMA16(kf, qf[1][kk], s[1][ck]);
            }
        }
        __builtin_amdgcn_s_setprio(0);
        // lane holds S[qg][q=l16][mem key = 32(ck>>1) + 8*lhi + 4(ck&1) + r]

        // per-lane LOCAL max (no shuffles in steady state)
        float tl[2];
        #pragma unroll
        for (int qg = 0; qg < 2; qg++) {
            tl[qg] = fmaxf(
                fmaxf(fmaxf(fmaxf(s[qg][0][0], s[qg][0][1]), fmaxf(s[qg][0][2], s[qg][0][3])),
                      fmaxf(fmaxf(s[qg][1][0], s[qg][1][1]), fmaxf(s[qg][1][2], s[qg][1][3]))),
                fmaxf(fmaxf(fmaxf(s[qg][2][0], s[qg][2][1]), fmaxf(s[qg][2][2], s[qg][2][3])),
                      fmaxf(fmaxf(s[qg][3][0], s[qg][3][1]), fmaxf(s[qg][3][2], s[qg][3][3]))));
        }

        // trigger iff any lane's local max grew > 8  (== full-row max test)
        if (!__all((tl[0] - m2[0] <= 8.0f) && (tl[1] - m2[1] <= 8.0f))) {
            #pragma unroll
            for (int qg = 0; qg < 2; qg++) {
                float tm = tl[qg];             // cross-lhi reduce only here
                tm = fmaxf(tm, __shfl_xor(tm, 16));
                tm = fmaxf(tm, __shfl_xor(tm, 32));
                float mn = fmaxf(m2[qg], tm);
                float sc = EXP2((m2[qg] - mn) * LOG2E);
                m2[qg] = mn; l[qg] *= sc;
                #pragma unroll
                for (int ct = 0; ct < 4; ct++)
                    #pragma unroll
                    for (int r = 0; r < 4; r++)
                        o[qg][ct][r] *= sc;
            }
        }

        // P = exp(s - m) in place; l += per-lane partial sum (no shuffles)
        #pragma unroll
        for (int qg = 0; qg < 2; qg++) {
            float nm2 = -m2[qg] * LOG2E;
            #pragma unroll
            for (int ck = 0; ck < 4; ck++)
                #pragma unroll
                for (int r = 0; r < 4; r++)
                    s[qg][ck][r] = EXP2(fmaf(s[qg][ck][r], LOG2E, nm2));
            l[qg] += ((s[qg][0][0] + s[qg][0][1]) + (s[qg][0][2] + s[qg][0][3]))
                   + ((s[qg][1][0] + s[qg][1][1]) + (s[qg][1][2] + s[qg][1][3]))
                   + ((s[qg][2][0] + s[qg][2][1]) + (s[qg][2][2] + s[qg][2][3]))
                   + ((s[qg][3][0] + s[qg][3][1]) + (s[qg][3][2] + s[qg][3][3]));
        }

        // PV: O^T += V * P^T.  vf shared by both q-groups (8 ds_read -> 16 MFMA)
        __builtin_amdgcn_s_setprio(1);
        #pragma unroll
        for (int kk2 = 0; kk2 < 2; kk2++) {
            f16x8 pb[2];
            #pragma unroll
            for (int qg = 0; qg < 2; qg++) {
                i32x4 w;
                w[0] = __builtin_bit_cast(int, __builtin_amdgcn_cvt_pkrtz(s[qg][2*kk2][0],   s[qg][2*kk2][1]));
                w[1] = __builtin_bit_cast(int, __builtin_amdgcn_cvt_pkrtz(s[qg][2*kk2][2],   s[qg][2*kk2][3]));
                w[2] = __builtin_bit_cast(int, __builtin_amdgcn_cvt_pkrtz(s[qg][2*kk2+1][0], s[qg][2*kk2+1][1]));
                w[3] = __builtin_bit_cast(int, __builtin_amdgcn_cvt_pkrtz(s[qg][2*kk2+1][2], s[qg][2*kk2+1][3]));
                pb[qg] = __builtin_bit_cast(f16x8, w);
            }
            #pragma unroll
            for (int ct = 0; ct < 4; ct++) {
                f16x8 vf = *(const f16x8*)&Vb[ct * 16 + l16][((kk2 * 4 + lhi) ^ (l16 & 7)) * 8];
                o[0][ct] = MFMA16(vf, pb[0], o[0][ct]);
                o[1][ct] = MFMA16(vf, pb[1], o[1][ct]);
            }
        }
        __builtin_amdgcn_s_setprio(0);

        if (t < 31) {                          // write t+1 into other buffer, then ONE barrier
            int nxt = cur ^ 1;
            *(f16x8*)&Ks[nxt][rp0][pchK * 8]       = kr0;
            *(f16x8*)&Ks[nxt][rp0 + 32][pchK * 8]  = kr1;
            *(f16x8*)&Vs[nxt][row0][pchV * 8]      = vr0;
            *(f16x8*)&Vs[nxt][row0 + 32][pchV * 8] = vr1;
            __syncthreads();
            cur = nxt;
        }
    }

    // epilogue: reduce l across lhi groups once, then y = o / l / 8
    const int b_ = bh >> 4, h_ = bh & 15;
    #pragma unroll
    for (int qg = 0; qg < 2; qg++) {
        float lf = l[qg];
        lf += __shfl_xor(lf, 16);
        lf += __shfl_xor(lf, 32);
        const int q = q0 + wv * 32 + qg * 16 + l16;
        const float inv = 1.0f / (lf * 8.0f);
        size_t rb = (size_t)(b_ * Tq + q) * Cdim + h_ * 64;
        #pragma unroll
        for (int ct = 0; ct < 4; ct++) {
            f16x4 y;
            #pragma unroll
            for (int r = 0; r < 4; r++) y[r] = (f16)(o[qg][ct][r] * inv);
            *(f16x4*)&Yc[rb + ct * 16 + lhi * 4] = y;
        }
    }
}

extern "C" void kernel_launch(void* const* d_in, const int* in_sizes, int n_in,
                              void* d_out, int out_size, void* d_ws, size_t ws_size,
                              hipStream_t stream)
{
    (void)in_sizes; (void)n_in; (void)out_size; (void)ws_size;
    const float* x  = (const float*)d_in[0];
    const float* Wa = (const float*)d_in[1];
    const float* ba = (const float*)d_in[2];
    const float* Wp = (const float*)d_in[3];
    const float* bp = (const float*)d_in[4];
    float* out = (float*)d_out;

    char* ws = (char*)d_ws;               // needs 48 MB
    f16* Xh  = (f16*)(ws);                //  8 MB  [4096][1024]
    f16* WaT = (f16*)(ws + (8u  << 20));  //  6 MB  [3072][1024]
    f16* WpT = (f16*)(ws + (14u << 20));  //  2 MB  [1024][1024]
    f16* Qc  = (f16*)(ws + (16u << 20));  //  8 MB  [32][2048][64]
    f16* Kc  = (f16*)(ws + (24u << 20));  //  8 MB  [32][2048][64]
    f16* Vt  = (f16*)(ws + (32u << 20));  //  8 MB  [32][64][2048]
    f16* Yc  = (f16*)(ws + (40u << 20));  //  8 MB  [4096][1024]

    k_cvt_x<<<4096, 256, 0, stream>>>(x, Xh);
    k_trans<<<dim3(48, 16), 256, 0, stream>>>(Wa, WaT, 1024, 3072);
    k_trans<<<dim3(16, 16), 256, 0, stream>>>(Wp, WpT, 1024, 1024);
    k_gemm<1><<<dim3(24, 32), 256, 0, stream>>>(Xh, WaT, ba, nullptr, Qc, Kc, Vt, 3072, 1024);
    k_attn<<<dim3(16, 32), 256, 0, stream>>>(Qc, Kc, Vt, Yc);
    k_gemmB<<<dim3(16, 32), 256, 0, stream>>>(Yc, WpT, bp, out, 1024, 1024);
}